// Round 15
// baseline (740.096 us; speedup 1.0000x reference)
//
#include <hip/hip_runtime.h>

#define D 128
#define RNUM 7
#define GNUM 64
#define LAYERS 3
#define NBA 8            // dest nodes per aggregation block (32 KB LDS tile)
#define ABT 512          // agg block threads (8 waves = 8 streams)
#define SEG_SHIFT 3      // segments = node*8 + rel (slot 7 empty)
#define KTOT 1024        // combined K: 896 (upd) + 128 (x)
#define SEGMASK (NBA * 8 - 1)
#define EPI_ITERS ((NBA * 448) / ABT)
#define NSHARD 8         // one scatter shard per XCD
#define BKC 64           // xform: K-cols per chunk
#define NCHUNK (KTOT / BKC)   // 16
#define XM 32            // xform: rows per block

typedef __attribute__((ext_vector_type(8))) short bf16x8;
typedef __attribute__((ext_vector_type(4))) float f32x4;

// ---------- CSR build: histogram over (dest node, rel) segments ----------
// (r10: fill/hist at scatter/atomic throughput floor; r7 form kept.)
__global__ __launch_bounds__(256) void hist_kernel(const int* __restrict__ nout,
    const int* __restrict__ rel, int* __restrict__ hist, int ne) {
  int e = blockIdx.x * 256 + threadIdx.x;
  if (e >= ne) return;
  int no = __builtin_nontemporal_load(&nout[e]);
  int r  = __builtin_nontemporal_load(&rel[e]);
  atomicAdd(&hist[(no << SEG_SHIFT) | r], 1);
}

// ---------- scan stage 1 ----------
__global__ __launch_bounds__(256) void scan1_kernel(const int* __restrict__ hist,
    int* __restrict__ row_ptr, int* __restrict__ partials, int nseg) {
  __shared__ int buf[256];
  const int t = threadIdx.x;
  const int base = blockIdx.x * 1024 + t * 4;
  int v0 = 0, v1 = 0, v2 = 0, v3 = 0;
  if (base + 3 < nseg) {
    int4 h4 = *(const int4*)&hist[base];
    v0 = h4.x; v1 = h4.y; v2 = h4.z; v3 = h4.w;
  } else {
    if (base + 0 < nseg) v0 = hist[base + 0];
    if (base + 1 < nseg) v1 = hist[base + 1];
    if (base + 2 < nseg) v2 = hist[base + 2];
    if (base + 3 < nseg) v3 = hist[base + 3];
  }
  int tsum = v0 + v1 + v2 + v3;
  buf[t] = tsum;
  __syncthreads();
  for (int off = 1; off < 256; off <<= 1) {
    int add = (t >= off) ? buf[t - off] : 0;
    __syncthreads();
    buf[t] += add;
    __syncthreads();
  }
  int incl = buf[t];
  int e0 = incl - tsum;
  int e1 = e0 + v0, e2 = e1 + v1, e3 = e2 + v2;
  if (base + 0 < nseg) row_ptr[base + 0] = e0;
  if (base + 1 < nseg) row_ptr[base + 1] = e1;
  if (base + 2 < nseg) row_ptr[base + 2] = e2;
  if (base + 3 < nseg) row_ptr[base + 3] = e3;
  if (t == 255) partials[blockIdx.x] = incl;
}

// ---------- scan stage 2 ----------
__global__ __launch_bounds__(256) void scan2_kernel(int* __restrict__ partials, int nb) {
  __shared__ int buf[256];
  __shared__ int carry_s;
  const int t = threadIdx.x;
  if (t == 0) carry_s = 0;
  __syncthreads();
  for (int c0 = 0; c0 < nb; c0 += 256) {
    int i = c0 + t;
    int v = (i < nb) ? partials[i] : 0;
    buf[t] = v;
    __syncthreads();
    for (int off = 1; off < 256; off <<= 1) {
      int add = (t >= off) ? buf[t - off] : 0;
      __syncthreads();
      buf[t] += add;
      __syncthreads();
    }
    int incl = buf[t];
    int excl = incl - v + carry_s;
    if (i < nb) partials[i] = excl;
    __syncthreads();
    if (t == 255) carry_s += incl;
    __syncthreads();
  }
}

// ---------- scan stage 3 ----------
__global__ __launch_bounds__(256) void scan3_kernel(int* __restrict__ row_ptr,
    int* __restrict__ cursor, const int* __restrict__ partials, int nseg, int ne) {
  int i = blockIdx.x * 256 + threadIdx.x;
  if (i < nseg) {
    int v = row_ptr[i] + partials[i >> 10];
    row_ptr[i] = v;
    cursor[i] = v;
  }
  if (i == 0) row_ptr[nseg] = ne;
}

// ---------- fill: (node_in | rel<<16 | dest_local<<19, ew) ----------
// r7 proven version. At the scatter throughput floor (~100 us); r10.
// dest_local widens to 3 bits (19..21) with NBA=8 — no field collision
// (nin < 2^16, rel 3 bits at 16..18).
__global__ __launch_bounds__(256) void fill_kernel(const int* __restrict__ nin,
    const int* __restrict__ nout, const int* __restrict__ rel,
    const float* __restrict__ ew, int* __restrict__ cursor,
    int2* __restrict__ erec, int ne, int nper) {
  const int shard = blockIdx.x & (NSHARD - 1);
  int e = (blockIdx.x >> 3) * 256 + threadIdx.x;
  if (e >= ne) return;
  int no = __builtin_nontemporal_load(&nout[e]);
  if ((int)((unsigned)no / (unsigned)nper) != shard) return;
  int r  = __builtin_nontemporal_load(&rel[e]);
  int ni = __builtin_nontemporal_load(&nin[e]);
  float w = __builtin_nontemporal_load(&ew[e]);
  int pos = atomicAdd(&cursor[(no << SEG_SHIFT) | r], 1);
  erec[pos] = make_int2(ni | (r << 16) | ((no & (NBA - 1)) << 19),
                        __float_as_int(w));
}

__device__ __forceinline__ unsigned int pack_bf2(float a, float b) {
  unsigned int ua = __float_as_uint(a), ub = __float_as_uint(b);
  ua = (ua + 0x7FFFu + ((ua >> 16) & 1u)) >> 16;
  ub = (ub + 0x7FFFu + ((ub >> 16) & 1u)) >> 16;
  return ua | (ub << 16);
}

__device__ __forceinline__ unsigned short bf1(float a) {
  unsigned int u = __float_as_uint(a);
  u = (u + 0x7FFFu + ((u >> 16) & 1u)) >> 16;
  return (unsigned short)u;
}

// ---------- W prep: Wt[layer][n][k] = bf16([Wrel;Wloop][k][n]) ----------
__global__ __launch_bounds__(256) void wt_prep_kernel(
    const float* __restrict__ Wrel, const float* __restrict__ Wloop,
    unsigned int* __restrict__ Wt32) {
  int tid = blockIdx.x * 256 + threadIdx.x;
  if (tid >= LAYERS * 128 * 512) return;
  int layer = tid >> 16;
  int rem = tid & 65535;
  int nrow = rem >> 9;
  int k = (rem & 511) * 2;
  float f0, f1;
  if (k < RNUM * D) {
    const float* base = Wrel + (size_t)layer * RNUM * D * D;
    f0 = base[(size_t)k * D + nrow];
    f1 = base[(size_t)(k + 1) * D + nrow];
  } else {
    const float* base = Wloop + (size_t)layer * D * D;
    f0 = base[(size_t)(k - RNUM * D) * D + nrow];
    f1 = base[(size_t)(k + 1 - RNUM * D) * D + nrow];
  }
  Wt32[tid] = pack_bf2(f0, f1);
}

// ---------- init: updx[m][896..1023] = bf16(emb[ut[m]][:]) ----------
__global__ __launch_bounds__(256) void initx_kernel(const int* __restrict__ ut,
    const float* __restrict__ emb, unsigned int* __restrict__ updx32, int n) {
  int tid = blockIdx.x * 256 + threadIdx.x;
  int node = tid >> 4, q = tid & 15;
  if (node >= n) return;
  const float4* E4 = (const float4*)emb;
  int u = ut[node];
  float4 f0 = E4[(size_t)u * 32 + q * 2];
  float4 f1 = E4[(size_t)u * 32 + q * 2 + 1];
  uint4 o;
  o.x = pack_bf2(f0.x, f0.y);
  o.y = pack_bf2(f0.z, f0.w);
  o.z = pack_bf2(f1.x, f1.y);
  o.w = pack_bf2(f1.z, f1.w);
  ((uint4*)&updx32[(size_t)node * 512 + 448])[q] = o;
}

// ---------- edge-parallel aggregation, register segmented-sum ----------
// r13 thin-VALU + 3-buffer structure, r15: NBA=8 with 512-thread blocks.
// 8 streams/block of the SAME ~32-edge length (r4 granularity lesson kept);
// 6250 blocks (was 12500) halves per-block fixed cost (launch slot, row_ptr
// loads, LDS-zero, 2 barriers, epilogue) per node. Occupancy unchanged:
// 4 blk x 8 waves = 32 waves/CU, LDS 4 x 32 KB = 128 <= 160 KB.
// seg id (local<<3)|rel still indexes acc_s[(node<<3)|rel] directly.
// Falsifier: agg >= 93.5 us -> per-block overhead immaterial, plateau.
__global__ __launch_bounds__(ABT) void agg_kernel(
    const int2* __restrict__ erec, const int* __restrict__ row_ptr,
    unsigned int* __restrict__ updx32, int n) {
  __shared__ float acc_s[NBA * 8 * D];   // 32 KB
  const int t = threadIdx.x;
  const int b0 = blockIdx.x * NBA;
#pragma unroll
  for (int i = 0; i < (NBA * 8 * D / 4) / ABT; ++i)
    ((float4*)acc_s)[t + i * ABT] = make_float4(0.f, 0.f, 0.f, 0.f);
  __syncthreads();

  int endn = b0 + NBA; if (endn > n) endn = n;
  const int es = row_ptr[b0 << SEG_SHIFT];
  const int ee = row_ptr[endn << SEG_SHIFT];
  const int cnt = ee - es;
  const int s = t >> 6;            // stream 0..7 == wave id
  const int lane = t & 63;         // 2-elem lane within 128-float row
  const int chunk = (cnt + (ABT / 64) - 1) / (ABT / 64);
  const int e0 = __builtin_amdgcn_readfirstlane(es + s * chunk);
  int eend = e0 + chunk; if (eend > ee) eend = ee;

  if (e0 < eend) {
    const int ngf = (eend - e0) >> 2;      // FULL groups (no padding)
    const int glast = (ngf > 0) ? ngf - 1 : 0;
    float accx = 0.f, accy = 0.f;
    bool first = true;
    int curseg;
    int2 rA[4], rB[4], rC[4];
    unsigned int pA[4], pB[4], pC[4];
    unsigned int sA[4], sB[4], sC[4];  // scalar copies of rec.x (SGPR)

#define LOADG(dst, g) do {                                          \
      int gg_ = ((g) < ngf) ? (g) : glast;                          \
      int base_ = e0 + (gg_ << 2);                                  \
      _Pragma("unroll")                                             \
      for (int j_ = 0; j_ < 4; ++j_)                                \
        (dst)[j_] = erec[base_ + j_];                               \
    } while (0)

#define GATHG(dst, sx, src) do {                                    \
      _Pragma("unroll")                                             \
      for (int j_ = 0; j_ < 4; ++j_) {                              \
        unsigned rx_ = (unsigned)__builtin_amdgcn_readfirstlane((src)[j_].x); \
        (sx)[j_] = rx_;                                             \
        const unsigned int* bp_ = updx32 + (size_t)(rx_ & 0xFFFFu) * 512u + 448u; \
        (dst)[j_] = bp_[lane];                                      \
      }                                                             \
    } while (0)

#define FLUSH_SEG() do {                                            \
      float* dst_ = &acc_s[curseg * D + (lane << 1)];               \
      if (first) {                                                  \
        atomicAdd(dst_ + 0, accx); atomicAdd(dst_ + 1, accy);       \
        first = false;                                              \
      } else {                                                      \
        *(float2*)dst_ = make_float2(accx, accy);                   \
      }                                                             \
      accx = 0.f; accy = 0.f;                                       \
    } while (0)

#define PROC4(sx, r, p) do {                                        \
      _Pragma("unroll")                                             \
      for (int j_ = 0; j_ < 4; ++j_) {                              \
        int sg_ = (int)(((sx)[j_] >> 16) & SEGMASK);                \
        if (sg_ != curseg) { FLUSH_SEG(); curseg = sg_; }           \
        float w_ = __int_as_float((r)[j_].y);                       \
        accx += w_ * __uint_as_float((p)[j_] << 16);                \
        accy += w_ * __uint_as_float((p)[j_] & 0xFFFF0000u);        \
      }                                                             \
    } while (0)

    if (ngf > 0) {
      LOADG(rA, 0);
      GATHG(pA, sA, rA);
      curseg = (int)((sA[0] >> 16) & SEGMASK);
      LOADG(rB, 1);
      GATHG(pB, sB, rB);
      LOADG(rC, 2);

      int g = 0;
      for (; g + 2 < ngf; g += 3) {
        GATHG(pC, sC, rC);
        PROC4(sA, rA, pA);
        LOADG(rA, g + 3);
        PROC4(sB, rB, pB);
        GATHG(pA, sA, rA);
        LOADG(rB, g + 4);
        PROC4(sC, rC, pC);
        GATHG(pB, sB, rB);
        LOADG(rC, g + 5);
      }
      int rem = ngf - g;           // 0, 1 or 2 full groups left
      if (rem >= 1) PROC4(sA, rA, pA);
      if (rem >= 2) PROC4(sB, rB, pB);
    } else {
      curseg = (int)(((unsigned)__builtin_amdgcn_readfirstlane(erec[e0].x) >> 16) & SEGMASK);
    }

    for (int e = e0 + (ngf << 2); e < eend; ++e) {
      int2 r0 = erec[e];
      unsigned rx_ = (unsigned)__builtin_amdgcn_readfirstlane(r0.x);
      const unsigned int* bp_ = updx32 + (size_t)(rx_ & 0xFFFFu) * 512u + 448u;
      unsigned int p0 = bp_[lane];
      int sg_ = (int)((rx_ >> 16) & SEGMASK);
      if (sg_ != curseg) { FLUSH_SEG(); curseg = sg_; }
      float w_ = __int_as_float(r0.y);
      accx += w_ * __uint_as_float(p0 << 16);
      accy += w_ * __uint_as_float(p0 & 0xFFFF0000u);
    }

    {
      float* dst_ = &acc_s[curseg * D + (lane << 1)];
      atomicAdd(dst_ + 0, accx); atomicAdd(dst_ + 1, accy);
    }
#undef PROC4
#undef FLUSH_SEG
#undef GATHG
#undef LOADG
  }
  __syncthreads();

  // flush tile -> updx rows (stride 512 uints), cols 0..447 (bf16 pairs)
  const int nvalid = endn - b0;
#pragma unroll
  for (int i = 0; i < EPI_ITERS; ++i) {
    int idx = t + i * ABT;            // 0..3583 over NBA x 448
    int node = idx / 448;
    int w448 = idx - node * 448;
    int rel = w448 >> 6;
    int k = (w448 * 2) & 127;
    if (node < nvalid) {
      float f0 = acc_s[((node << 3) | rel) * D + k];
      float f1 = acc_s[((node << 3) | rel) * D + k + 1];
      updx32[(size_t)(b0 + node) * 512 + w448] = pack_bf2(f0, f1);
    }
  }
}

__device__ __forceinline__ void barrier_fence() {
  asm volatile("s_waitcnt lgkmcnt(0)" ::: "memory");
  __builtin_amdgcn_s_barrier();
  asm volatile("" ::: "memory");
}

// ---------- MFMA transform, LDS-staged A, double-buffered A and B ----------
// h = relu( updx(N x 1024 bf16) @ Wt^T + biases ).
// r14 M=32 version (measured equal to M=64; occupancy theory null).
// Block = 4 waves over 32 rows x 128 cols; wave = 32 rows x 32 cols.
// A HBM->regs (2 ahead) -> LDS (1 ahead, XOR-swizzle); B bank reloaded
// only after COMPUTE consumed it (r3 fix).
__global__ __launch_bounds__(256) void xform_kernel(
    unsigned short* __restrict__ updx, const unsigned short* __restrict__ Wt,
    const float* __restrict__ brel, const float* __restrict__ bloop,
    float* __restrict__ hout, int n, int write_fp32) {
  __shared__ unsigned short Atile[2][XM * BKC];   // 2 x 4 KB
  const int t = threadIdx.x;
  const int w = t >> 6, lane = t & 63;
  const int rt = lane & 15, quad = lane >> 4;
  const int m0 = blockIdx.x * XM;

  // B: wave w covers output cols [w*32, w*32+32)
  const unsigned short* bp0 = Wt + (size_t)(w * 32 + rt) * KTOT + quad * 8;
  const unsigned short* bp1 = bp0 + (size_t)16 * KTOT;

  // A staging: thread t owns unit t: row=t>>3, slot j=t&7.
  const int r0_ = t >> 3, j0_ = t & 7;
  const unsigned short* ga0 = updx + (size_t)(m0 + r0_) * KTOT + (j0_ << 3);
  const int ldsu0 = r0_ * BKC + ((j0_ ^ (r0_ & 7)) << 3);

  f32x4 acc[2][2];
#pragma unroll
  for (int i = 0; i < 2; ++i)
#pragma unroll
    for (int c = 0; c < 2; ++c) acc[i][c] = (f32x4){0.f, 0.f, 0.f, 0.f};

  uint4 gA0[2];             // staged A regs, bank = chunk&1
  bf16x8 B[2][2][2];        // [bank][cc][kk]

#define ISSUE_A(bank, c_) do {                                      \
    const int kc_ = (c_) * BKC;                                     \
    gA0[bank] = *(const uint4*)(ga0 + kc_);                         \
  } while (0)

#define ISSUE_B(bank, c_) do {                                      \
    const int kc_ = (c_) * BKC;                                     \
    B[bank][0][0] = *(const bf16x8*)(bp0 + kc_);                    \
    B[bank][0][1] = *(const bf16x8*)(bp0 + kc_ + 32);               \
    B[bank][1][0] = *(const bf16x8*)(bp1 + kc_);                    \
    B[bank][1][1] = *(const bf16x8*)(bp1 + kc_ + 32);               \
  } while (0)

#define WRITE_A(bank) do {                                          \
    *(uint4*)&Atile[bank][ldsu0] = gA0[bank];                       \
  } while (0)

#define COMPUTE(bank) do {                                          \
    _Pragma("unroll")                                               \
    for (int kk_ = 0; kk_ < 2; ++kk_) {                             \
      _Pragma("unroll")                                             \
      for (int r4_ = 0; r4_ < 2; ++r4_) {                           \
        const int row_ = r4_ * 16 + rt;                             \
        const int off_ = ((kk_ * 64 + quad * 16) ^ ((rt & 7) << 4)) >> 1; \
        bf16x8 a_ = *(const bf16x8*)&Atile[bank][row_ * BKC + off_]; \
        acc[r4_][0] = __builtin_amdgcn_mfma_f32_16x16x32_bf16(a_, B[bank][0][kk_], acc[r4_][0], 0, 0, 0); \
        acc[r4_][1] = __builtin_amdgcn_mfma_f32_16x16x32_bf16(a_, B[bank][1][kk_], acc[r4_][1], 0, 0, 0); \
      }                                                             \
    }                                                               \
  } while (0)

  // prologue: chunk0 A+B, chunk1 A+B in flight; chunk0 A -> LDS bank 0
  ISSUE_A(0, 0); ISSUE_B(0, 0);
  ISSUE_A(1, 1); ISSUE_B(1, 1);
  WRITE_A(0);               // compiler waits on gA[0] loads only
  barrier_fence();

#pragma unroll
  for (int c = 0; c < NCHUNK; c += 2) {
    // even chunk (bank 0)
    if (c + 2 < NCHUNK) ISSUE_A(0, c + 2);
    COMPUTE(0);                            // consumes Atile[0], B[0] = chunk c
    if (c + 2 < NCHUNK) ISSUE_B(0, c + 2); // B bank0 free only now
    WRITE_A(1);                            // chunk c+1 -> LDS bank 1
    barrier_fence();
    // odd chunk (bank 1)
    if (c + 3 < NCHUNK) ISSUE_A(1, c + 3);
    COMPUTE(1);                            // consumes Atile[1], B[1] = chunk c+1
    if (c + 3 < NCHUNK) ISSUE_B(1, c + 3);
    if (c + 2 < NCHUNK) {
      WRITE_A(0);                          // chunk c+2 -> LDS bank 0
      barrier_fence();
    }
  }
#undef COMPUTE
#undef WRITE_A
#undef ISSUE_B
#undef ISSUE_A

  // C/D layout: col = lane&15, row = quad*4 + reg
#pragma unroll
  for (int r4 = 0; r4 < 2; ++r4) {
#pragma unroll
    for (int cc = 0; cc < 2; ++cc) {
      int col = w * 32 + cc * 16 + rt;
      float bias = brel[col] + bloop[col];
#pragma unroll
      for (int r = 0; r < 4; ++r) {
        int m = m0 + r4 * 16 + quad * 4 + r;
        if (m < n) {
          float v = fmaxf(acc[r4][cc][r] + bias, 0.f);
          if (write_fp32) hout[(size_t)m * D + col] = v;
          else updx[(size_t)m * KTOT + 896 + col] = bf1(v);
        }
      }
    }
  }
}

// ---------- graph pooling (node2graph sorted) ----------
__global__ __launch_bounds__(256) void pool_kernel(const float* __restrict__ x,
    const int* __restrict__ n2g, float* __restrict__ gf, int n) {
  int d = threadIdx.x & 127;
  int sub = threadIdx.x >> 7;
  int n0 = (blockIdx.x * 2 + sub) * 128;
  int nend = n0 + 128;
  if (nend > n) nend = n;
  float acc = 0.f;
  int gcur = -1;
  for (int i = n0; i < nend; ++i) {
    int g = n2g[i];
    if (g != gcur) {
      if (gcur >= 0) atomicAdd(&gf[gcur * D + d], acc);
      gcur = g;
      acc = 0.f;
    }
    acc += x[(size_t)i * D + d];
  }
  if (gcur >= 0) atomicAdd(&gf[gcur * D + d], acc);
}

extern "C" void kernel_launch(void* const* d_in, const int* in_sizes, int n_in,
                              void* d_out, int out_size, void* d_ws, size_t ws_size,
                              hipStream_t stream) {
  const int*   unit_type  = (const int*)d_in[0];
  const int*   node_in    = (const int*)d_in[1];
  const int*   node_out   = (const int*)d_in[2];
  const int*   relation   = (const int*)d_in[3];
  const float* edge_w     = (const float*)d_in[4];
  const int*   node2graph = (const int*)d_in[5];
  const float* emb        = (const float*)d_in[6];
  const float* W_rel      = (const float*)d_in[7];
  const float* b_rel      = (const float*)d_in[8];
  const float* W_loop     = (const float*)d_in[9];
  const float* b_loop     = (const float*)d_in[10];

  const int n  = in_sizes[0];
  const int ne = in_sizes[1];
  float* out = (float*)d_out;

  const int nseg = n << SEG_SHIFT;
  const int nb   = (nseg + 1023) / 1024;
  const int nper = (n + NSHARD - 1) / NSHARD;

  // workspace layout
  unsigned short* updx     = (unsigned short*)d_ws;               // N x 1024 bf16
  unsigned short* Wt       = updx + (size_t)n * KTOT;             // 3 x 128 x 1024 bf16
  int2*           erec     = (int2*)(Wt + (size_t)LAYERS * D * KTOT);
  int*            hist     = (int*)(erec + ne);
  int*            row_ptr  = hist + nseg;
  int*            cursor   = row_ptr + ((nseg + 4) & ~3);
  int*            partials = cursor + nseg;

  hipMemsetAsync(d_out, 0, (size_t)GNUM * D * sizeof(float), stream);
  hipMemsetAsync(hist, 0, (size_t)nseg * sizeof(int), stream);

  const int eblocks = (ne + 255) / 256;
  hist_kernel<<<eblocks, 256, 0, stream>>>(node_out, relation, hist, ne);
  scan1_kernel<<<nb, 256, 0, stream>>>(hist, row_ptr, partials, nseg);
  scan2_kernel<<<1, 256, 0, stream>>>(partials, nb);
  scan3_kernel<<<(nseg + 255) / 256, 256, 0, stream>>>(row_ptr, cursor, partials, nseg, ne);
  fill_kernel<<<eblocks * NSHARD, 256, 0, stream>>>(node_in, node_out, relation,
                                                    edge_w, cursor, erec, ne, nper);

  wt_prep_kernel<<<(LAYERS * 128 * 512 + 255) / 256, 256, 0, stream>>>(
      W_rel, W_loop, (unsigned int*)Wt);

  initx_kernel<<<(n * 16 + 255) / 256, 256, 0, stream>>>(
      unit_type, emb, (unsigned int*)updx, n);

  const int ablocks = (n + NBA - 1) / NBA;
  const int tblocks = (n + XM - 1) / XM;
  float* xfinal = out + GNUM * D;
  for (int i = 0; i < LAYERS; ++i) {
    agg_kernel<<<ablocks, ABT, 0, stream>>>(erec, row_ptr,
                                            (unsigned int*)updx, n);
    xform_kernel<<<tblocks, 256, 0, stream>>>(
        updx, Wt + (size_t)i * D * KTOT,
        b_rel + (size_t)i * D, b_loop + (size_t)i * D,
        xfinal, n, (i == LAYERS - 1) ? 1 : 0);
  }

  pool_kernel<<<(n + 255) / 256, 256, 0, stream>>>(xfinal, node2graph, out, n);
}

// Round 16
// 731.355 us; speedup vs baseline: 1.0120x; 1.0120x over previous
//
#include <hip/hip_runtime.h>

#define D 128
#define RNUM 7
#define GNUM 64
#define LAYERS 3
#define NBA 4            // dest nodes per aggregation block (16 KB LDS tile)
#define SEG_SHIFT 3      // segments = node*8 + rel (slot 7 empty)
#define KTOT 1024        // combined K: 896 (upd) + 128 (x)
#define SEGMASK (NBA * 8 - 1)
#define EPI_ITERS ((NBA * 448) / 256)
#define NSHARD 8         // one scatter shard per XCD
#define BKC 64           // xform: K-cols per chunk
#define NCHUNK (KTOT / BKC)   // 16
#define XM 32            // xform: rows per block

typedef __attribute__((ext_vector_type(8))) short bf16x8;
typedef __attribute__((ext_vector_type(4))) float f32x4;

// ---------- CSR build: histogram over (dest node, rel) segments ----------
// (r10: fill/hist at scatter/atomic throughput floor; r7 form kept.)
__global__ __launch_bounds__(256) void hist_kernel(const int* __restrict__ nout,
    const int* __restrict__ rel, int* __restrict__ hist, int ne) {
  int e = blockIdx.x * 256 + threadIdx.x;
  if (e >= ne) return;
  int no = __builtin_nontemporal_load(&nout[e]);
  int r  = __builtin_nontemporal_load(&rel[e]);
  atomicAdd(&hist[(no << SEG_SHIFT) | r], 1);
}

// ---------- scan stage 1 ----------
__global__ __launch_bounds__(256) void scan1_kernel(const int* __restrict__ hist,
    int* __restrict__ row_ptr, int* __restrict__ partials, int nseg) {
  __shared__ int buf[256];
  const int t = threadIdx.x;
  const int base = blockIdx.x * 1024 + t * 4;
  int v0 = 0, v1 = 0, v2 = 0, v3 = 0;
  if (base + 3 < nseg) {
    int4 h4 = *(const int4*)&hist[base];
    v0 = h4.x; v1 = h4.y; v2 = h4.z; v3 = h4.w;
  } else {
    if (base + 0 < nseg) v0 = hist[base + 0];
    if (base + 1 < nseg) v1 = hist[base + 1];
    if (base + 2 < nseg) v2 = hist[base + 2];
    if (base + 3 < nseg) v3 = hist[base + 3];
  }
  int tsum = v0 + v1 + v2 + v3;
  buf[t] = tsum;
  __syncthreads();
  for (int off = 1; off < 256; off <<= 1) {
    int add = (t >= off) ? buf[t - off] : 0;
    __syncthreads();
    buf[t] += add;
    __syncthreads();
  }
  int incl = buf[t];
  int e0 = incl - tsum;
  int e1 = e0 + v0, e2 = e1 + v1, e3 = e2 + v2;
  if (base + 0 < nseg) row_ptr[base + 0] = e0;
  if (base + 1 < nseg) row_ptr[base + 1] = e1;
  if (base + 2 < nseg) row_ptr[base + 2] = e2;
  if (base + 3 < nseg) row_ptr[base + 3] = e3;
  if (t == 255) partials[blockIdx.x] = incl;
}

// ---------- scan stage 2 ----------
__global__ __launch_bounds__(256) void scan2_kernel(int* __restrict__ partials, int nb) {
  __shared__ int buf[256];
  __shared__ int carry_s;
  const int t = threadIdx.x;
  if (t == 0) carry_s = 0;
  __syncthreads();
  for (int c0 = 0; c0 < nb; c0 += 256) {
    int i = c0 + t;
    int v = (i < nb) ? partials[i] : 0;
    buf[t] = v;
    __syncthreads();
    for (int off = 1; off < 256; off <<= 1) {
      int add = (t >= off) ? buf[t - off] : 0;
      __syncthreads();
      buf[t] += add;
      __syncthreads();
    }
    int incl = buf[t];
    int excl = incl - v + carry_s;
    if (i < nb) partials[i] = excl;
    __syncthreads();
    if (t == 255) carry_s += incl;
    __syncthreads();
  }
}

// ---------- scan stage 3 ----------
__global__ __launch_bounds__(256) void scan3_kernel(int* __restrict__ row_ptr,
    int* __restrict__ cursor, const int* __restrict__ partials, int nseg, int ne) {
  int i = blockIdx.x * 256 + threadIdx.x;
  if (i < nseg) {
    int v = row_ptr[i] + partials[i >> 10];
    row_ptr[i] = v;
    cursor[i] = v;
  }
  if (i == 0) row_ptr[nseg] = ne;
}

// ---------- fill: (node_in | rel<<16 | dest_local<<19, ew) ----------
// r7 proven version. At the scatter throughput floor (~100 us); r10.
__global__ __launch_bounds__(256) void fill_kernel(const int* __restrict__ nin,
    const int* __restrict__ nout, const int* __restrict__ rel,
    const float* __restrict__ ew, int* __restrict__ cursor,
    int2* __restrict__ erec, int ne, int nper) {
  const int shard = blockIdx.x & (NSHARD - 1);
  int e = (blockIdx.x >> 3) * 256 + threadIdx.x;
  if (e >= ne) return;
  int no = __builtin_nontemporal_load(&nout[e]);
  if ((int)((unsigned)no / (unsigned)nper) != shard) return;
  int r  = __builtin_nontemporal_load(&rel[e]);
  int ni = __builtin_nontemporal_load(&nin[e]);
  float w = __builtin_nontemporal_load(&ew[e]);
  int pos = atomicAdd(&cursor[(no << SEG_SHIFT) | r], 1);
  erec[pos] = make_int2(ni | (r << 16) | ((no & (NBA - 1)) << 19),
                        __float_as_int(w));
}

__device__ __forceinline__ unsigned int pack_bf2(float a, float b) {
  unsigned int ua = __float_as_uint(a), ub = __float_as_uint(b);
  ua = (ua + 0x7FFFu + ((ua >> 16) & 1u)) >> 16;
  ub = (ub + 0x7FFFu + ((ub >> 16) & 1u)) >> 16;
  return ua | (ub << 16);
}

__device__ __forceinline__ unsigned short bf1(float a) {
  unsigned int u = __float_as_uint(a);
  u = (u + 0x7FFFu + ((u >> 16) & 1u)) >> 16;
  return (unsigned short)u;
}

// ---------- W prep: Wt[layer][n][k] = bf16([Wrel;Wloop][k][n]) ----------
__global__ __launch_bounds__(256) void wt_prep_kernel(
    const float* __restrict__ Wrel, const float* __restrict__ Wloop,
    unsigned int* __restrict__ Wt32) {
  int tid = blockIdx.x * 256 + threadIdx.x;
  if (tid >= LAYERS * 128 * 512) return;
  int layer = tid >> 16;
  int rem = tid & 65535;
  int nrow = rem >> 9;
  int k = (rem & 511) * 2;
  float f0, f1;
  if (k < RNUM * D) {
    const float* base = Wrel + (size_t)layer * RNUM * D * D;
    f0 = base[(size_t)k * D + nrow];
    f1 = base[(size_t)(k + 1) * D + nrow];
  } else {
    const float* base = Wloop + (size_t)layer * D * D;
    f0 = base[(size_t)(k - RNUM * D) * D + nrow];
    f1 = base[(size_t)(k + 1 - RNUM * D) * D + nrow];
  }
  Wt32[tid] = pack_bf2(f0, f1);
}

// ---------- init: updx[m][896..1023] = bf16(emb[ut[m]][:]) ----------
__global__ __launch_bounds__(256) void initx_kernel(const int* __restrict__ ut,
    const float* __restrict__ emb, unsigned int* __restrict__ updx32, int n) {
  int tid = blockIdx.x * 256 + threadIdx.x;
  int node = tid >> 4, q = tid & 15;
  if (node >= n) return;
  const float4* E4 = (const float4*)emb;
  int u = ut[node];
  float4 f0 = E4[(size_t)u * 32 + q * 2];
  float4 f1 = E4[(size_t)u * 32 + q * 2 + 1];
  uint4 o;
  o.x = pack_bf2(f0.x, f0.y);
  o.y = pack_bf2(f0.z, f0.w);
  o.z = pack_bf2(f1.x, f1.y);
  o.w = pack_bf2(f1.z, f1.w);
  ((uint4*)&updx32[(size_t)node * 512 + 448])[q] = o;
}

// ---------- edge-parallel aggregation, register segmented-sum ----------
// r13 structure (NBA=4 reverted from r15's regression) + r16: RECORD LOADS
// FORCED ONTO THE VECTOR PIPE. r12/r13 counters (VGPR=16, SGPR=64) show
// records went to s_load. SMEM completes OUT-OF-ORDER vs lgkmcnt, so any
// record use forces s_waitcnt lgkmcnt(0) — draining ALL outstanding
// s_loads including the prefetched next groups. The 3-buffer record
// prefetch was therefore a sync point, exposing a full K$-miss latency
// per iteration (explains the r13 null). Fix: pin the group base address
// in a VGPR (empty asm "+v") -> global_load_dwordx2 (vmcnt: in-order,
// individually countable; prefetches stay in flight across consumption).
// rec.x still readfirstlane'd to SGPR for the gather base (r12 win kept).
__global__ __launch_bounds__(256) void agg_kernel(
    const int2* __restrict__ erec, const int* __restrict__ row_ptr,
    unsigned int* __restrict__ updx32, int n) {
  __shared__ float acc_s[NBA * 8 * D];   // 16 KB
  const int t = threadIdx.x;
  const int b0 = blockIdx.x * NBA;
#pragma unroll
  for (int i = 0; i < NBA; ++i)
    ((float4*)acc_s)[t + i * 256] = make_float4(0.f, 0.f, 0.f, 0.f);
  __syncthreads();

  int endn = b0 + NBA; if (endn > n) endn = n;
  const int es = row_ptr[b0 << SEG_SHIFT];
  const int ee = row_ptr[endn << SEG_SHIFT];
  const int cnt = ee - es;
  const int s = t >> 6;            // stream 0..3 == wave id
  const int lane = t & 63;         // 2-elem lane within 128-float row
  const int chunk = (cnt + 3) >> 2;
  const int e0 = __builtin_amdgcn_readfirstlane(es + s * chunk);
  int eend = e0 + chunk; if (eend > ee) eend = ee;

  if (e0 < eend) {
    const int ngf = (eend - e0) >> 2;      // FULL groups (no padding)
    const int glast = (ngf > 0) ? ngf - 1 : 0;
    float accx = 0.f, accy = 0.f;
    bool first = true;
    int curseg;
    int2 rA[4], rB[4], rC[4];
    unsigned int pA[4], pB[4], pC[4];
    unsigned int sA[4], sB[4], sC[4];  // scalar copies of rec.x (SGPR)

// group load with VGPR-pinned base -> global_load (vmcnt), prefetchable
#define LOADG(dst, g) do {                                          \
      int gg_ = ((g) < ngf) ? (g) : glast;                          \
      int base_ = e0 + (gg_ << 2);                                  \
      asm volatile("" : "+v"(base_));                               \
      _Pragma("unroll")                                             \
      for (int j_ = 0; j_ < 4; ++j_)                                \
        (dst)[j_] = erec[base_ + j_];                               \
    } while (0)

// gather with SGPR row base; per-lane offset only
#define GATHG(dst, sx, src) do {                                    \
      _Pragma("unroll")                                             \
      for (int j_ = 0; j_ < 4; ++j_) {                              \
        unsigned rx_ = (unsigned)__builtin_amdgcn_readfirstlane((src)[j_].x); \
        (sx)[j_] = rx_;                                             \
        const unsigned int* bp_ = updx32 + (size_t)(rx_ & 0xFFFFu) * 512u + 448u; \
        (dst)[j_] = bp_[lane];                                      \
      }                                                             \
    } while (0)

#define FLUSH_SEG() do {                                            \
      float* dst_ = &acc_s[curseg * D + (lane << 1)];               \
      if (first) {                                                  \
        atomicAdd(dst_ + 0, accx); atomicAdd(dst_ + 1, accy);       \
        first = false;                                              \
      } else {                                                      \
        *(float2*)dst_ = make_float2(accx, accy);                   \
      }                                                             \
      accx = 0.f; accy = 0.f;                                       \
    } while (0)

#define PROC4(sx, r, p) do {                                        \
      _Pragma("unroll")                                             \
      for (int j_ = 0; j_ < 4; ++j_) {                              \
        int sg_ = (int)(((sx)[j_] >> 16) & SEGMASK);                \
        if (sg_ != curseg) { FLUSH_SEG(); curseg = sg_; }           \
        float w_ = __int_as_float((r)[j_].y);                       \
        accx += w_ * __uint_as_float((p)[j_] << 16);                \
        accy += w_ * __uint_as_float((p)[j_] & 0xFFFF0000u);        \
      }                                                             \
    } while (0)

    if (ngf > 0) {
      LOADG(rA, 0);
      GATHG(pA, sA, rA);
      curseg = (int)((sA[0] >> 16) & SEGMASK);
      LOADG(rB, 1);
      GATHG(pB, sB, rB);
      LOADG(rC, 2);

      int g = 0;
      for (; g + 2 < ngf; g += 3) {
        GATHG(pC, sC, rC);
        PROC4(sA, rA, pA);
        LOADG(rA, g + 3);
        PROC4(sB, rB, pB);
        GATHG(pA, sA, rA);
        LOADG(rB, g + 4);
        PROC4(sC, rC, pC);
        GATHG(pB, sB, rB);
        LOADG(rC, g + 5);
      }
      int rem = ngf - g;           // 0, 1 or 2 full groups left
      if (rem >= 1) PROC4(sA, rA, pA);
      if (rem >= 2) PROC4(sB, rB, pB);
    } else {
      curseg = (int)(((unsigned)__builtin_amdgcn_readfirstlane(erec[e0].x) >> 16) & SEGMASK);
    }

    for (int e = e0 + (ngf << 2); e < eend; ++e) {
      int2 r0 = erec[e];
      unsigned rx_ = (unsigned)__builtin_amdgcn_readfirstlane(r0.x);
      const unsigned int* bp_ = updx32 + (size_t)(rx_ & 0xFFFFu) * 512u + 448u;
      unsigned int p0 = bp_[lane];
      int sg_ = (int)((rx_ >> 16) & SEGMASK);
      if (sg_ != curseg) { FLUSH_SEG(); curseg = sg_; }
      float w_ = __int_as_float(r0.y);
      accx += w_ * __uint_as_float(p0 << 16);
      accy += w_ * __uint_as_float(p0 & 0xFFFF0000u);
    }

    {
      float* dst_ = &acc_s[curseg * D + (lane << 1)];
      atomicAdd(dst_ + 0, accx); atomicAdd(dst_ + 1, accy);
    }
#undef PROC4
#undef FLUSH_SEG
#undef GATHG
#undef LOADG
  }
  __syncthreads();

  // flush tile -> updx rows (stride 512 uints), cols 0..447 (bf16 pairs)
  const int nvalid = endn - b0;
#pragma unroll
  for (int i = 0; i < EPI_ITERS; ++i) {
    int idx = t + i * 256;            // 0..1791 over NBA x 448
    int node = idx / 448;
    int w448 = idx - node * 448;
    int rel = w448 >> 6;
    int k = (w448 * 2) & 127;
    if (node < nvalid) {
      float f0 = acc_s[((node << 3) | rel) * D + k];
      float f1 = acc_s[((node << 3) | rel) * D + k + 1];
      updx32[(size_t)(b0 + node) * 512 + w448] = pack_bf2(f0, f1);
    }
  }
}

__device__ __forceinline__ void barrier_fence() {
  asm volatile("s_waitcnt lgkmcnt(0)" ::: "memory");
  __builtin_amdgcn_s_barrier();
  asm volatile("" ::: "memory");
}

// ---------- MFMA transform, LDS-staged A, double-buffered A and B ----------
// h = relu( updx(N x 1024 bf16) @ Wt^T + biases ).
// r14 M=32 version (measured equal to M=64; occupancy theory null).
// Block = 4 waves over 32 rows x 128 cols; wave = 32 rows x 32 cols.
// A HBM->regs (2 ahead) -> LDS (1 ahead, XOR-swizzle); B bank reloaded
// only after COMPUTE consumed it (r3 fix).
__global__ __launch_bounds__(256) void xform_kernel(
    unsigned short* __restrict__ updx, const unsigned short* __restrict__ Wt,
    const float* __restrict__ brel, const float* __restrict__ bloop,
    float* __restrict__ hout, int n, int write_fp32) {
  __shared__ unsigned short Atile[2][XM * BKC];   // 2 x 4 KB
  const int t = threadIdx.x;
  const int w = t >> 6, lane = t & 63;
  const int rt = lane & 15, quad = lane >> 4;
  const int m0 = blockIdx.x * XM;

  // B: wave w covers output cols [w*32, w*32+32)
  const unsigned short* bp0 = Wt + (size_t)(w * 32 + rt) * KTOT + quad * 8;
  const unsigned short* bp1 = bp0 + (size_t)16 * KTOT;

  // A staging: thread t owns unit t: row=t>>3, slot j=t&7.
  const int r0_ = t >> 3, j0_ = t & 7;
  const unsigned short* ga0 = updx + (size_t)(m0 + r0_) * KTOT + (j0_ << 3);
  const int ldsu0 = r0_ * BKC + ((j0_ ^ (r0_ & 7)) << 3);

  f32x4 acc[2][2];
#pragma unroll
  for (int i = 0; i < 2; ++i)
#pragma unroll
    for (int c = 0; c < 2; ++c) acc[i][c] = (f32x4){0.f, 0.f, 0.f, 0.f};

  uint4 gA0[2];             // staged A regs, bank = chunk&1
  bf16x8 B[2][2][2];        // [bank][cc][kk]

#define ISSUE_A(bank, c_) do {                                      \
    const int kc_ = (c_) * BKC;                                     \
    gA0[bank] = *(const uint4*)(ga0 + kc_);                         \
  } while (0)

#define ISSUE_B(bank, c_) do {                                      \
    const int kc_ = (c_) * BKC;                                     \
    B[bank][0][0] = *(const bf16x8*)(bp0 + kc_);                    \
    B[bank][0][1] = *(const bf16x8*)(bp0 + kc_ + 32);               \
    B[bank][1][0] = *(const bf16x8*)(bp1 + kc_);                    \
    B[bank][1][1] = *(const bf16x8*)(bp1 + kc_ + 32);               \
  } while (0)

#define WRITE_A(bank) do {                                          \
    *(uint4*)&Atile[bank][ldsu0] = gA0[bank];                       \
  } while (0)

#define COMPUTE(bank) do {                                          \
    _Pragma("unroll")                                               \
    for (int kk_ = 0; kk_ < 2; ++kk_) {                             \
      _Pragma("unroll")                                             \
      for (int r4_ = 0; r4_ < 2; ++r4_) {                           \
        const int row_ = r4_ * 16 + rt;                             \
        const int off_ = ((kk_ * 64 + quad * 16) ^ ((rt & 7) << 4)) >> 1; \
        bf16x8 a_ = *(const bf16x8*)&Atile[bank][row_ * BKC + off_]; \
        acc[r4_][0] = __builtin_amdgcn_mfma_f32_16x16x32_bf16(a_, B[bank][0][kk_], acc[r4_][0], 0, 0, 0); \
        acc[r4_][1] = __builtin_amdgcn_mfma_f32_16x16x32_bf16(a_, B[bank][1][kk_], acc[r4_][1], 0, 0, 0); \
      }                                                             \
    }                                                               \
  } while (0)

  // prologue: chunk0 A+B, chunk1 A+B in flight; chunk0 A -> LDS bank 0
  ISSUE_A(0, 0); ISSUE_B(0, 0);
  ISSUE_A(1, 1); ISSUE_B(1, 1);
  WRITE_A(0);               // compiler waits on gA[0] loads only
  barrier_fence();

#pragma unroll
  for (int c = 0; c < NCHUNK; c += 2) {
    // even chunk (bank 0)
    if (c + 2 < NCHUNK) ISSUE_A(0, c + 2);
    COMPUTE(0);                            // consumes Atile[0], B[0] = chunk c
    if (c + 2 < NCHUNK) ISSUE_B(0, c + 2); // B bank0 free only now
    WRITE_A(1);                            // chunk c+1 -> LDS bank 1
    barrier_fence();
    // odd chunk (bank 1)
    if (c + 3 < NCHUNK) ISSUE_A(1, c + 3);
    COMPUTE(1);                            // consumes Atile[1], B[1] = chunk c+1
    if (c + 3 < NCHUNK) ISSUE_B(1, c + 3);
    if (c + 2 < NCHUNK) {
      WRITE_A(0);                          // chunk c+2 -> LDS bank 0
      barrier_fence();
    }
  }
#undef COMPUTE
#undef WRITE_A
#undef ISSUE_B
#undef ISSUE_A

  // C/D layout: col = lane&15, row = quad*4 + reg
#pragma unroll
  for (int r4 = 0; r4 < 2; ++r4) {
#pragma unroll
    for (int cc = 0; cc < 2; ++cc) {
      int col = w * 32 + cc * 16 + rt;
      float bias = brel[col] + bloop[col];
#pragma unroll
      for (int r = 0; r < 4; ++r) {
        int m = m0 + r4 * 16 + quad * 4 + r;
        if (m < n) {
          float v = fmaxf(acc[r4][cc][r] + bias, 0.f);
          if (write_fp32) hout[(size_t)m * D + col] = v;
          else updx[(size_t)m * KTOT + 896 + col] = bf1(v);
        }
      }
    }
  }
}

// ---------- graph pooling (node2graph sorted) ----------
__global__ __launch_bounds__(256) void pool_kernel(const float* __restrict__ x,
    const int* __restrict__ n2g, float* __restrict__ gf, int n) {
  int d = threadIdx.x & 127;
  int sub = threadIdx.x >> 7;
  int n0 = (blockIdx.x * 2 + sub) * 128;
  int nend = n0 + 128;
  if (nend > n) nend = n;
  float acc = 0.f;
  int gcur = -1;
  for (int i = n0; i < nend; ++i) {
    int g = n2g[i];
    if (g != gcur) {
      if (gcur >= 0) atomicAdd(&gf[gcur * D + d], acc);
      gcur = g;
      acc = 0.f;
    }
    acc += x[(size_t)i * D + d];
  }
  if (gcur >= 0) atomicAdd(&gf[gcur * D + d], acc);
}

extern "C" void kernel_launch(void* const* d_in, const int* in_sizes, int n_in,
                              void* d_out, int out_size, void* d_ws, size_t ws_size,
                              hipStream_t stream) {
  const int*   unit_type  = (const int*)d_in[0];
  const int*   node_in    = (const int*)d_in[1];
  const int*   node_out   = (const int*)d_in[2];
  const int*   relation   = (const int*)d_in[3];
  const float* edge_w     = (const float*)d_in[4];
  const int*   node2graph = (const int*)d_in[5];
  const float* emb        = (const float*)d_in[6];
  const float* W_rel      = (const float*)d_in[7];
  const float* b_rel      = (const float*)d_in[8];
  const float* W_loop     = (const float*)d_in[9];
  const float* b_loop     = (const float*)d_in[10];

  const int n  = in_sizes[0];
  const int ne = in_sizes[1];
  float* out = (float*)d_out;

  const int nseg = n << SEG_SHIFT;
  const int nb   = (nseg + 1023) / 1024;
  const int nper = (n + NSHARD - 1) / NSHARD;

  // workspace layout
  unsigned short* updx     = (unsigned short*)d_ws;               // N x 1024 bf16
  unsigned short* Wt       = updx + (size_t)n * KTOT;             // 3 x 128 x 1024 bf16
  int2*           erec     = (int2*)(Wt + (size_t)LAYERS * D * KTOT);
  int*            hist     = (int*)(erec + ne);
  int*            row_ptr  = hist + nseg;
  int*            cursor   = row_ptr + ((nseg + 4) & ~3);
  int*            partials = cursor + nseg;

  hipMemsetAsync(d_out, 0, (size_t)GNUM * D * sizeof(float), stream);
  hipMemsetAsync(hist, 0, (size_t)nseg * sizeof(int), stream);

  const int eblocks = (ne + 255) / 256;
  hist_kernel<<<eblocks, 256, 0, stream>>>(node_out, relation, hist, ne);
  scan1_kernel<<<nb, 256, 0, stream>>>(hist, row_ptr, partials, nseg);
  scan2_kernel<<<1, 256, 0, stream>>>(partials, nb);
  scan3_kernel<<<(nseg + 255) / 256, 256, 0, stream>>>(row_ptr, cursor, partials, nseg, ne);
  fill_kernel<<<eblocks * NSHARD, 256, 0, stream>>>(node_in, node_out, relation,
                                                    edge_w, cursor, erec, ne, nper);

  wt_prep_kernel<<<(LAYERS * 128 * 512 + 255) / 256, 256, 0, stream>>>(
      W_rel, W_loop, (unsigned int*)Wt);

  initx_kernel<<<(n * 16 + 255) / 256, 256, 0, stream>>>(
      unit_type, emb, (unsigned int*)updx, n);

  const int ablocks = (n + NBA - 1) / NBA;
  const int tblocks = (n + XM - 1) / XM;
  float* xfinal = out + GNUM * D;
  for (int i = 0; i < LAYERS; ++i) {
    agg_kernel<<<ablocks, 256, 0, stream>>>(erec, row_ptr,
                                            (unsigned int*)updx, n);
    xform_kernel<<<tblocks, 256, 0, stream>>>(
        updx, Wt + (size_t)i * D * KTOT,
        b_rel + (size_t)i * D, b_loop + (size_t)i * D,
        xfinal, n, (i == LAYERS - 1) ? 1 : 0);
  }

  pool_kernel<<<(n + 255) / 256, 256, 0, stream>>>(xfinal, node2graph, out, n);
}